// Round 1
// baseline (860.188 us; speedup 1.0000x reference)
//
#include <hip/hip_runtime.h>
#include <hip/hip_bf16.h>

// MHCLayer: B=8192, N=4, C=4096, fp32 in/out.
// One block per batch row b. 256 threads; each thread owns 4 float4 chunks
// (16 c-values) across all 4 streams -> 16 float4 loads held in registers.
// x read once (512 MiB), out written once (512 MiB): HBM-bound, ~170us floor.

constexpr int Bb = 8192;
constexpr int Nn = 4;
constexpr int Cc = 4096;
constexpr int THREADS = 256;
constexpr int C4 = Cc / 4;          // 1024 float4 per stream row
constexpr int VPT = C4 / THREADS;   // 4 float4 chunks per thread

__global__ __launch_bounds__(THREADS)
void mhc_kernel(const float* __restrict__ x,
                const float* __restrict__ w,
                const float* __restrict__ H_pre,
                const float* __restrict__ H_post,
                const float* __restrict__ H_res,
                float* __restrict__ out)
{
    const int b = blockIdx.x;
    const int t = threadIdx.x;

    // ---- tiny scalar prep, redundant per thread (params are L2-resident) ----
    float pre[4], post[4], P[4][4];
#pragma unroll
    for (int n = 0; n < 4; ++n) {
        pre[n]  = 1.0f / (1.0f + expf(-H_pre[n]));
        post[n] = 2.0f / (1.0f + expf(-H_post[n]));
    }
#pragma unroll
    for (int i = 0; i < 4; ++i)
#pragma unroll
        for (int j = 0; j < 4; ++j)
            P[i][j] = expf(H_res[i * 4 + j]);
#pragma unroll
    for (int it = 0; it < 3; ++it) {
#pragma unroll
        for (int i = 0; i < 4; ++i) {
            float s = P[i][0] + P[i][1] + P[i][2] + P[i][3] + 1e-6f;
            float r = 1.0f / s;
#pragma unroll
            for (int j = 0; j < 4; ++j) P[i][j] *= r;
        }
#pragma unroll
        for (int j = 0; j < 4; ++j) {
            float s = P[0][j] + P[1][j] + P[2][j] + P[3][j] + 1e-6f;
            float r = 1.0f / s;
#pragma unroll
            for (int i = 0; i < 4; ++i) P[i][j] *= r;
        }
    }

    // ---- load this row's x entirely into registers (coalesced float4) ----
    const float4* xb = (const float4*)(x + (size_t)b * Nn * Cc);
    float4 xv[4][VPT];  // [stream n][chunk v]
#pragma unroll
    for (int n = 0; n < 4; ++n)
#pragma unroll
        for (int v = 0; v < VPT; ++v)
            xv[n][v] = xb[n * C4 + v * THREADS + t];

    // ---- sigmoid-gated aggregate, bf16 round-trip, sum of squares ----
    float4 aggbf[VPT];
    float ssq = 0.0f;
#pragma unroll
    for (int v = 0; v < VPT; ++v) {
        float4 a;
        a.x = pre[0]*xv[0][v].x + pre[1]*xv[1][v].x + pre[2]*xv[2][v].x + pre[3]*xv[3][v].x;
        a.y = pre[0]*xv[0][v].y + pre[1]*xv[1][v].y + pre[2]*xv[2][v].y + pre[3]*xv[3][v].y;
        a.z = pre[0]*xv[0][v].z + pre[1]*xv[1][v].z + pre[2]*xv[2][v].z + pre[3]*xv[3][v].z;
        a.w = pre[0]*xv[0][v].w + pre[1]*xv[1][v].w + pre[2]*xv[2][v].w + pre[3]*xv[3][v].w;
        // bf16 round-trip (RNE) to mirror the .astype(bfloat16).astype(float32)
        a.x = __bfloat162float(__float2bfloat16(a.x));
        a.y = __bfloat162float(__float2bfloat16(a.y));
        a.z = __bfloat162float(__float2bfloat16(a.z));
        a.w = __bfloat162float(__float2bfloat16(a.w));
        ssq += a.x*a.x + a.y*a.y + a.z*a.z + a.w*a.w;
        aggbf[v] = a;
    }

    // ---- block reduction of ssq over 256 threads (4 waves) ----
#pragma unroll
    for (int off = 32; off > 0; off >>= 1)
        ssq += __shfl_down(ssq, off, 64);
    __shared__ float wsum[4];
    const int wid  = t >> 6;
    const int lane = t & 63;
    if (lane == 0) wsum[wid] = ssq;
    __syncthreads();
    const float tot = wsum[0] + wsum[1] + wsum[2] + wsum[3];
    const float rms_inv = 1.0f / sqrtf(tot * (1.0f / (float)Cc) + 1e-6f);

    // ---- emit: out[b,i,c] = sum_j P[i][j]*x[b,j,c] + post[i]*y_norm[c] ----
    const float4* w4 = (const float4*)w;
    float4* ob = (float4*)(out + (size_t)b * Nn * Cc);
#pragma unroll
    for (int v = 0; v < VPT; ++v) {
        const int idx = v * THREADS + t;
        const float4 wv = w4[idx];
        float4 yn;
        yn.x = aggbf[v].x * rms_inv * wv.x;
        yn.y = aggbf[v].y * rms_inv * wv.y;
        yn.z = aggbf[v].z * rms_inv * wv.z;
        yn.w = aggbf[v].w * rms_inv * wv.w;
#pragma unroll
        for (int i = 0; i < 4; ++i) {
            float4 o;
            o.x = P[i][0]*xv[0][v].x + P[i][1]*xv[1][v].x + P[i][2]*xv[2][v].x + P[i][3]*xv[3][v].x + post[i]*yn.x;
            o.y = P[i][0]*xv[0][v].y + P[i][1]*xv[1][v].y + P[i][2]*xv[2][v].y + P[i][3]*xv[3][v].y + post[i]*yn.y;
            o.z = P[i][0]*xv[0][v].z + P[i][1]*xv[1][v].z + P[i][2]*xv[2][v].z + P[i][3]*xv[3][v].z + post[i]*yn.z;
            o.w = P[i][0]*xv[0][v].w + P[i][1]*xv[1][v].w + P[i][2]*xv[2][v].w + P[i][3]*xv[3][v].w + post[i]*yn.w;
            ob[i * C4 + idx] = o;
        }
    }
}

extern "C" void kernel_launch(void* const* d_in, const int* in_sizes, int n_in,
                              void* d_out, int out_size, void* d_ws, size_t ws_size,
                              hipStream_t stream) {
    const float* x      = (const float*)d_in[0];
    const float* w      = (const float*)d_in[1];
    const float* H_pre  = (const float*)d_in[2];
    const float* H_post = (const float*)d_in[3];
    const float* H_res  = (const float*)d_in[4];
    float* out = (float*)d_out;
    mhc_kernel<<<Bb, THREADS, 0, stream>>>(x, w, H_pre, H_post, H_res, out);
}

// Round 2
// 848.602 us; speedup vs baseline: 1.0137x; 1.0137x over previous
//
#include <hip/hip_runtime.h>
#include <hip/hip_bf16.h>

// MHCLayer: B=8192, N=4, C=4096, fp32 in/out. HBM-bound (~1.07 GB total).
//
// Two kernels:
//  1) prep: 1 thread computes sigmoid(H_pre), 2*sigmoid(H_post), and the
//     3-iter Sinkhorn projection of exp(H_res) -> 24 floats in d_ws.
//  2) main: one 1024-thread block per batch row b. Thread t owns float4
//     column t (VPT=1): 4 float4 loads (one per stream), aggregate + bf16
//     round-trip + block RMS reduction, then 4 float4 stores. Live VGPRs
//     ~55 (params come in as wave-uniform s_loads) -> full occupancy,
//     no spills.

constexpr int Bb = 8192;
constexpr int Cc = 4096;
constexpr int C4 = Cc / 4;          // 1024 float4 per stream row
constexpr int THREADS = 1024;       // == C4, VPT = 1

__global__ __launch_bounds__(64)
void mhc_prep(const float* __restrict__ H_pre,
              const float* __restrict__ H_post,
              const float* __restrict__ H_res,
              float* __restrict__ prm)  // [0..3]=pre [4..7]=post [8..23]=P row-major
{
    if (threadIdx.x != 0) return;
    float P[4][4];
    for (int i = 0; i < 4; ++i)
        for (int j = 0; j < 4; ++j)
            P[i][j] = expf(H_res[i * 4 + j]);
    for (int it = 0; it < 3; ++it) {
        for (int i = 0; i < 4; ++i) {
            float r = 1.0f / (P[i][0] + P[i][1] + P[i][2] + P[i][3] + 1e-6f);
            for (int j = 0; j < 4; ++j) P[i][j] *= r;
        }
        for (int j = 0; j < 4; ++j) {
            float r = 1.0f / (P[0][j] + P[1][j] + P[2][j] + P[3][j] + 1e-6f);
            for (int i = 0; i < 4; ++i) P[i][j] *= r;
        }
    }
    for (int n = 0; n < 4; ++n) {
        prm[n]     = 1.0f / (1.0f + expf(-H_pre[n]));
        prm[4 + n] = 2.0f / (1.0f + expf(-H_post[n]));
    }
    for (int k = 0; k < 16; ++k) prm[8 + k] = P[k >> 2][k & 3];
}

__global__ __launch_bounds__(THREADS)
void mhc_main(const float* __restrict__ x,
              const float* __restrict__ w,
              const float* __restrict__ prm,
              float* __restrict__ out)
{
    const int b = blockIdx.x;
    const int t = threadIdx.x;           // float4 column index, 0..1023

    // wave-uniform parameter loads -> SGPRs
    float pre[4], post[4], P[4][4];
#pragma unroll
    for (int n = 0; n < 4; ++n) {
        pre[n]  = prm[n];
        post[n] = prm[4 + n];
    }
#pragma unroll
    for (int i = 0; i < 4; ++i)
#pragma unroll
        for (int j = 0; j < 4; ++j)
            P[i][j] = prm[8 + i * 4 + j];

    // ---- load: one float4 per stream (coalesced, 64 KiB per block) ----
    const float4* xb = (const float4*)(x + (size_t)b * 4 * Cc);
    float4 x0 = xb[t];
    float4 x1 = xb[C4 + t];
    float4 x2 = xb[2 * C4 + t];
    float4 x3 = xb[3 * C4 + t];

    // ---- sigmoid-gated aggregate + bf16 round-trip (RNE) ----
    float4 a;
    a.x = pre[0]*x0.x + pre[1]*x1.x + pre[2]*x2.x + pre[3]*x3.x;
    a.y = pre[0]*x0.y + pre[1]*x1.y + pre[2]*x2.y + pre[3]*x3.y;
    a.z = pre[0]*x0.z + pre[1]*x1.z + pre[2]*x2.z + pre[3]*x3.z;
    a.w = pre[0]*x0.w + pre[1]*x1.w + pre[2]*x2.w + pre[3]*x3.w;
    a.x = __bfloat162float(__float2bfloat16(a.x));
    a.y = __bfloat162float(__float2bfloat16(a.y));
    a.z = __bfloat162float(__float2bfloat16(a.z));
    a.w = __bfloat162float(__float2bfloat16(a.w));
    float ssq = a.x*a.x + a.y*a.y + a.z*a.z + a.w*a.w;

    // ---- block reduction over 16 waves for RMS ----
#pragma unroll
    for (int off = 32; off > 0; off >>= 1)
        ssq += __shfl_down(ssq, off, 64);
    __shared__ float wsum[16];
    const int wid  = t >> 6;
    const int lane = t & 63;
    if (lane == 0) wsum[wid] = ssq;
    __syncthreads();
    float tot = 0.0f;
#pragma unroll
    for (int k = 0; k < 16; ++k) tot += wsum[k];
    const float rms_inv = 1.0f / sqrtf(tot * (1.0f / (float)Cc) + 1e-6f);

    // ---- emit 4 output streams ----
    const float4 wv = ((const float4*)w)[t];
    float4 yn;
    yn.x = a.x * rms_inv * wv.x;
    yn.y = a.y * rms_inv * wv.y;
    yn.z = a.z * rms_inv * wv.z;
    yn.w = a.w * rms_inv * wv.w;

    float4* ob = (float4*)(out + (size_t)b * 4 * Cc);
#pragma unroll
    for (int i = 0; i < 4; ++i) {
        float4 o;
        o.x = P[i][0]*x0.x + P[i][1]*x1.x + P[i][2]*x2.x + P[i][3]*x3.x + post[i]*yn.x;
        o.y = P[i][0]*x0.y + P[i][1]*x1.y + P[i][2]*x2.y + P[i][3]*x3.y + post[i]*yn.y;
        o.z = P[i][0]*x0.z + P[i][1]*x1.z + P[i][2]*x2.z + P[i][3]*x3.z + post[i]*yn.z;
        o.w = P[i][0]*x0.w + P[i][1]*x1.w + P[i][2]*x2.w + P[i][3]*x3.w + post[i]*yn.w;
        ob[i * C4 + t] = o;
    }
}

extern "C" void kernel_launch(void* const* d_in, const int* in_sizes, int n_in,
                              void* d_out, int out_size, void* d_ws, size_t ws_size,
                              hipStream_t stream) {
    const float* x      = (const float*)d_in[0];
    const float* w      = (const float*)d_in[1];
    const float* H_pre  = (const float*)d_in[2];
    const float* H_post = (const float*)d_in[3];
    const float* H_res  = (const float*)d_in[4];
    float* prm = (float*)d_ws;
    float* out = (float*)d_out;

    mhc_prep<<<1, 64, 0, stream>>>(H_pre, H_post, H_res, prm);
    mhc_main<<<Bb, THREADS, 0, stream>>>(x, w, prm, out);
}